// Round 5
// baseline (394.099 us; speedup 1.0000x reference)
//
#include <hip/hip_runtime.h>
#include <stdint.h>
#include <stddef.h>

typedef __fp16 f16;
typedef __attribute__((ext_vector_type(8))) __fp16 half8;
typedef __attribute__((ext_vector_type(4))) __fp16 half4;
typedef __attribute__((ext_vector_type(4))) float f32x4;

static __device__ __forceinline__ f32x4 mfma16(half8 a, half8 b, f32x4 c) {
    return __builtin_amdgcn_mfma_f32_16x16x32_f16(a, b, c, 0, 0, 0);
}
static __device__ __forceinline__ float fexp2(float x) { float r; asm("v_exp_f32 %0, %1" : "=v"(r) : "v"(x)); return r; }
static __device__ __forceinline__ float frcp(float x)  { float r; asm("v_rcp_f32 %0, %1" : "=v"(r) : "v"(x)); return r; }

static constexpr float L2E  = 1.4426950408889634f;
static constexpr float L2E2 = 2.8853900817779268f;

static constexpr int LDA = 264;    // LDS row stride (f16), 528B rows, 16B aligned
static constexpr int LDF2 = 520;   // f2 buffer stride, 1040B rows

// ---------------- workspace layout (bytes) ----------------
static constexpr size_t OFF_EMB   = 0;
static constexpr size_t OFF_WQIH  = 3200000;
static constexpr size_t OFF_WQHH  = OFF_WQIH + 8192;
static constexpr size_t OFF_WSIH  = OFF_WQHH + 8192;
static constexpr size_t OFF_WSHH  = OFF_WSIH + 8192;
static constexpr size_t OFF_BQ    = OFF_WSHH + 8192;
static constexpr size_t OFF_BS    = OFF_BQ + 512;
static constexpr size_t OFF_G1WP  = OFF_BS + 512;
static constexpr size_t OFF_BIAS8 = OFF_G1WP + 32768;
static constexpr size_t OFF_G2W   = OFF_BIAS8 + 8192;
static constexpr size_t OFF_G3W   = OFF_G2W + 131072;
static constexpr size_t OFF_G4W   = OFF_G3W + 131072;
static constexpr size_t OFF_F1W   = OFF_G4W + 131072;
static constexpr size_t OFF_F2W   = OFF_F1W + 131072;
static constexpr size_t OFF_F3W   = OFF_F2W + 262144;
static constexpr size_t OFF_HS    = OFF_F3W + 1024000;
static constexpr size_t OFF_HQ    = OFF_HS + 2097152;
static constexpr size_t OFF_ACT2  = OFF_HQ + 262144;
static constexpr size_t WS_NEED   = OFF_ACT2 + 16777216;

// ---------------- fused fp32->fp16 conversion + small prep ----------------
struct CvtJobs { const float* src[7]; f16* dst[7]; int n[7]; };

__global__ __launch_bounds__(256) void cvt_prep(
    CvtJobs j,
    const float* __restrict__ g1W, const float* __restrict__ g1b,
    f16* __restrict__ wp, float* __restrict__ bias8,
    const float* __restrict__ qWih, const float* __restrict__ qWhh, const float* __restrict__ qb,
    const float* __restrict__ sWih, const float* __restrict__ sWhh, const float* __restrict__ sb,
    f16* __restrict__ wqih, f16* __restrict__ wqhh, float* __restrict__ bq,
    f16* __restrict__ wsih, f16* __restrict__ wshh, float* __restrict__ bs)
{
    int t = threadIdx.x;
    if (blockIdx.y < 7) {
        int jb = blockIdx.y;
        int i = (blockIdx.x * 256 + t) * 8;
        if (i >= j.n[jb]) return;
        const float* s = j.src[jb] + i;
        f32x4 a = *(const f32x4*)s;
        f32x4 b = *(const f32x4*)(s + 4);
        half8 o;
        o[0]=(f16)a[0]; o[1]=(f16)a[1]; o[2]=(f16)a[2]; o[3]=(f16)a[3];
        o[4]=(f16)b[0]; o[5]=(f16)b[1]; o[6]=(f16)b[2]; o[7]=(f16)b[3];
        *(half8*)(j.dst[jb] + i) = o;
        return;
    }
    if (blockIdx.x == 0) {
        int col = t;
        for (int k = 0; k < 64; k++) wp[col * 64 + k] = (f16)g1W[col * 65 + k];
        float wpos = g1W[col * 65 + 64];
        float b = g1b[col];
        for (int i = 0; i < 8; i++) bias8[i * 256 + col] = b + (float)i * wpos;
    } else if (blockIdx.x == 1) {
        for (int i = t; i < 4096; i += 256) {
            int row = i >> 5;
            float s = (row < 64 || row >= 96) ? -L2E : L2E2;
            wqih[i] = (f16)(qWih[i] * s);
            wqhh[i] = (f16)(qWhh[i] * s);
            wsih[i] = (f16)(sWih[i] * s);
            wshh[i] = (f16)(sWhh[i] * s);
        }
        if (t < 128) {
            float s = (t < 64 || t >= 96) ? -L2E : L2E2;
            bq[t] = qb[t] * s;
            bs[t] = sb[t] * s;
        }
    }
}

// ---------------- fused LSTM: one wave = 2 independent groups of 16 samples ----------------
struct SfPtrs { const int* p[8]; };

__global__ __launch_bounds__(64) void lstm_kernel(
    SfPtrs sf, const int* __restrict__ qtok, const f16* __restrict__ emb_h,
    const f16* __restrict__ wih_sf, const f16* __restrict__ whh_sf, const float* __restrict__ b_sf,
    const f16* __restrict__ wih_q,  const f16* __restrict__ whh_q,  const float* __restrict__ b_q,
    f16* __restrict__ hs_out, f16* __restrict__ hq_out)
{
    __shared__ __align__(16) char hb0[16 * 80];
    __shared__ __align__(16) char hb1[16 * 80];
    int lane = threadIdx.x;
    int c15 = lane & 15, kq = lane >> 4;
    int sbase = blockIdx.x * 32;              // 1152 blocks; sf/q boundary at 32768 is 32-aligned
    bool isq = sbase >= 32768;
    const f16* wih = isq ? wih_q : wih_sf;
    const f16* whh = isq ? whh_q : whh_sf;
    const float* bvec = isq ? b_q : b_sf;

    half8 wi[8], wh[8];
    f32x4 bc[8];
    #pragma unroll
    for (int n = 0; n < 8; n++) {
        wi[n] = *(const half8*)(wih + (n * 16 + c15) * 32 + kq * 8);
        wh[n] = *(const half8*)(whh + (n * 16 + c15) * 32 + kq * 8);
        bc[n] = *(const f32x4*)(bvec + n * 16 + kq * 4);
    }
    int sg0 = sbase + c15, sg1 = sbase + 16 + c15;
    const int* tp0; const int* tp1;
    if (isq) { tp0 = qtok + (sg0 - 32768) * 64; tp1 = qtok + (sg1 - 32768) * 64; }
    else     { tp0 = sf.p[sg0 >> 12] + (sg0 & 4095) * 64;
               tp1 = sf.p[sg1 >> 12] + (sg1 & 4095) * 64; }

    f32x4 zro = {0.f, 0.f, 0.f, 0.f};
    *(f32x4*)(hb0 + lane * 16) = zro;
    *(f32x4*)(hb1 + lane * 16) = zro;
    if (lane < 16) { *(f32x4*)(hb0 + 1024 + lane * 16) = zro;
                     *(f32x4*)(hb1 + 1024 + lane * 16) = zro; }

    float cst0[2][4] = {}, cst1[2][4] = {};
    const char* hrd0 = hb0 + c15 * 80 + kq * 16;
    const char* hrd1 = hb1 + c15 * 80 + kq * 16;

    half8 xf0 = *(const half8*)(emb_h + (size_t)tp0[0] * 32 + kq * 8);
    half8 xf1 = *(const half8*)(emb_h + (size_t)tp1[0] * 32 + kq * 8);

    #pragma unroll 1
    for (int t = 0; t < 64; t++) {
        half8 hf0 = *(const half8*)hrd0;
        half8 hf1 = *(const half8*)hrd1;
        f32x4 a0[8], a1[8];
        #pragma unroll
        for (int n = 0; n < 8; n++) a0[n] = mfma16(wi[n], xf0, bc[n]);
        #pragma unroll
        for (int n = 0; n < 8; n++) a1[n] = mfma16(wi[n], xf1, bc[n]);
        #pragma unroll
        for (int n = 0; n < 8; n++) a0[n] = mfma16(wh[n], hf0, a0[n]);
        #pragma unroll
        for (int n = 0; n < 8; n++) a1[n] = mfma16(wh[n], hf1, a1[n]);
        if (t < 63) {
            xf0 = *(const half8*)(emb_h + (size_t)tp0[t + 1] * 32 + kq * 8);
            xf1 = *(const half8*)(emb_h + (size_t)tp1[t + 1] * 32 + kq * 8);
        }
        // group 0 gate math (VALU/trans here overlaps group 1's MFMA latency)
        #pragma unroll
        for (int jh = 0; jh < 2; jh++) {
            half4 hp;
            #pragma unroll
            for (int r = 0; r < 4; r++) {
                float ei = fexp2(a0[0 + jh][r]);
                float ef = fexp2(a0[2 + jh][r]);
                float eg = fexp2(a0[4 + jh][r]);
                float eo = fexp2(a0[6 + jh][r]);
                float t1 = 1.f + ei, t2 = 1.f + ef, t5 = 1.f + eo;
                float eg1 = eg + 1.f, egm = eg - 1.f;
                float num = fmaf(egm, t2, cst0[jh][r] * t1 * eg1);
                float cn  = num * frcp((t2 * t1) * eg1);
                cst0[jh][r] = cn;
                float ec  = fexp2(cn * L2E2);
                hp[r] = (f16)((ec - 1.f) * frcp((ec + 1.f) * t5));
            }
            *(half4*)(hb0 + c15 * 80 + jh * 32 + kq * 8) = hp;
        }
        // group 1 gate math
        #pragma unroll
        for (int jh = 0; jh < 2; jh++) {
            half4 hp;
            #pragma unroll
            for (int r = 0; r < 4; r++) {
                float ei = fexp2(a1[0 + jh][r]);
                float ef = fexp2(a1[2 + jh][r]);
                float eg = fexp2(a1[4 + jh][r]);
                float eo = fexp2(a1[6 + jh][r]);
                float t1 = 1.f + ei, t2 = 1.f + ef, t5 = 1.f + eo;
                float eg1 = eg + 1.f, egm = eg - 1.f;
                float num = fmaf(egm, t2, cst1[jh][r] * t1 * eg1);
                float cn  = num * frcp((t2 * t1) * eg1);
                cst1[jh][r] = cn;
                float ec  = fexp2(cn * L2E2);
                hp[r] = (f16)((ec - 1.f) * frcp((ec + 1.f) * t5));
            }
            *(half4*)(hb1 + c15 * 80 + jh * 32 + kq * 8) = hp;
        }
    }
    half8 hv0 = *(const half8*)hrd0;
    half8 hv1 = *(const half8*)hrd1;
    if (isq) {
        *(half8*)(hq_out + (size_t)(sg0 - 32768) * 32 + kq * 8) = hv0;
        *(half8*)(hq_out + (size_t)(sg1 - 32768) * 32 + kq * 8) = hv1;
    } else {
        *(half8*)(hs_out + (size_t)sg0 * 32 + kq * 8) = hv0;
        *(half8*)(hs_out + (size_t)sg1 * 32 + kq * 8) = hv1;
    }
}

// ---------------- fused g1..g4: 64-row strips, 8 waves (2 row x 4 col) ----------------
template<bool TOGLOBAL>
static __device__ __forceinline__ void layer256(
    const f16 (* __restrict__ src)[LDA], f16 (* __restrict__ dst)[LDA],
    const f16* __restrict__ W, const float* __restrict__ bias,
    f16* __restrict__ gout, int m0, int wm, int wn, int c15, int kq)
{
    f32x4 acc[2][4];
    #pragma unroll
    for (int a = 0; a < 2; a++)
        #pragma unroll
        for (int b = 0; b < 4; b++) acc[a][b] = (f32x4){0.f, 0.f, 0.f, 0.f};
    #pragma unroll
    for (int k0 = 0; k0 < 8; k0++) {
        half8 av[2], bv[4];
        #pragma unroll
        for (int fm = 0; fm < 2; fm++) av[fm] = *(const half8*)(&src[wm * 32 + fm * 16 + c15][k0 * 32 + kq * 8]);
        #pragma unroll
        for (int fn = 0; fn < 4; fn++) bv[fn] = *(const half8*)(W + (size_t)(wn * 64 + fn * 16 + c15) * 256 + k0 * 32 + kq * 8);
        #pragma unroll
        for (int fm = 0; fm < 2; fm++)
            #pragma unroll
            for (int fn = 0; fn < 4; fn++) acc[fm][fn] = mfma16(av[fm], bv[fn], acc[fm][fn]);
    }
    #pragma unroll
    for (int fn = 0; fn < 4; fn++) {
        int col = wn * 64 + fn * 16 + c15;
        float bb = bias[col];
        #pragma unroll
        for (int fm = 0; fm < 2; fm++)
            #pragma unroll
            for (int r = 0; r < 4; r++) {
                float v = fmaxf(acc[fm][fn][r] + bb, 0.f);
                int row = wm * 32 + fm * 16 + kq * 4 + r;
                if (TOGLOBAL) gout[(size_t)(m0 + row) * 256 + col] = (f16)v;
                else          dst[row][col] = (f16)v;
            }
    }
}

__global__ __launch_bounds__(512) void gemm_g1234(
    const f16* __restrict__ hs, const f16* __restrict__ hq,
    const f16* __restrict__ g1wp, const float* __restrict__ bias8,
    const f16* __restrict__ g2w, const float* __restrict__ g2b,
    const f16* __restrict__ g3w, const float* __restrict__ g3b,
    const f16* __restrict__ g4w, const float* __restrict__ g4b,
    f16* __restrict__ act2)
{
    __shared__ __align__(16) f16 actA[64][LDA];
    __shared__ __align__(16) f16 actB[64][LDA];
    const int wv = threadIdx.x >> 6, lane = threadIdx.x & 63;
    const int c15 = lane & 15, kq = lane >> 4;
    const int wm = wv >> 2, wn = wv & 3;
    const int m0 = blockIdx.x * 64;
    const float* brow = bias8 + ((m0 >> 12) << 8);

    { // g1: K=64 (hs || hq)
        f32x4 acc[2][4];
        #pragma unroll
        for (int a = 0; a < 2; a++)
            #pragma unroll
            for (int b = 0; b < 4; b++) acc[a][b] = (f32x4){0.f, 0.f, 0.f, 0.f};
        half8 av[2], bv[4];
        #pragma unroll
        for (int fm = 0; fm < 2; fm++) av[fm] = *(const half8*)(hs + (size_t)(m0 + wm * 32 + fm * 16 + c15) * 32 + kq * 8);
        #pragma unroll
        for (int fn = 0; fn < 4; fn++) bv[fn] = *(const half8*)(g1wp + (size_t)(wn * 64 + fn * 16 + c15) * 64 + kq * 8);
        #pragma unroll
        for (int fm = 0; fm < 2; fm++)
            #pragma unroll
            for (int fn = 0; fn < 4; fn++) acc[fm][fn] = mfma16(av[fm], bv[fn], acc[fm][fn]);
        #pragma unroll
        for (int fm = 0; fm < 2; fm++) av[fm] = *(const half8*)(hq + (size_t)((m0 + wm * 32 + fm * 16 + c15) & 4095) * 32 + kq * 8);
        #pragma unroll
        for (int fn = 0; fn < 4; fn++) bv[fn] = *(const half8*)(g1wp + (size_t)(wn * 64 + fn * 16 + c15) * 64 + 32 + kq * 8);
        #pragma unroll
        for (int fm = 0; fm < 2; fm++)
            #pragma unroll
            for (int fn = 0; fn < 4; fn++) acc[fm][fn] = mfma16(av[fm], bv[fn], acc[fm][fn]);
        #pragma unroll
        for (int fn = 0; fn < 4; fn++) {
            int col = wn * 64 + fn * 16 + c15;
            float bb = brow[col];
            #pragma unroll
            for (int fm = 0; fm < 2; fm++)
                #pragma unroll
                for (int r = 0; r < 4; r++)
                    actA[wm * 32 + fm * 16 + kq * 4 + r][col] = (f16)fmaxf(acc[fm][fn][r] + bb, 0.f);
        }
    }
    __syncthreads();
    layer256<false>(actA, actB, g2w, g2b, nullptr, m0, wm, wn, c15, kq);
    __syncthreads();
    layer256<false>(actB, actA, g3w, g3b, nullptr, m0, wm, wn, c15, kq);
    __syncthreads();
    layer256<true>(actA, actB, g4w, g4b, act2, m0, wm, wn, c15, kq);
}

// ---------------- fused sum8 + f1 + f2 + f3: 16-row strips, 8 waves ----------------
__global__ __launch_bounds__(512) void f123s_kernel(
    const f16* __restrict__ act2,
    const f16* __restrict__ f1w, const float* __restrict__ f1b,
    const f16* __restrict__ f2w, const float* __restrict__ f2b,
    const f16* __restrict__ f3w, const float* __restrict__ f3b,
    float* __restrict__ out)
{
    __shared__ __align__(16) f16 smbuf[16][LDA];
    __shared__ __align__(16) f16 f1buf[16][LDA];
    __shared__ __align__(16) f16 f2buf[16][LDF2];
    const int b0 = blockIdx.x * 16;

    { // segment-sum: 512 threads, thread t -> row t>>5, cols (t&31)*8..+7
        int r = threadIdx.x >> 5, cb = (threadIdx.x & 31) * 8;
        float s[8] = {};
        #pragma unroll
        for (int i = 0; i < 8; i++) {
            half8 v = *(const half8*)(act2 + ((size_t)(i * 4096 + b0 + r)) * 256 + cb);
            #pragma unroll
            for (int q = 0; q < 8; q++) s[q] += (float)v[q];
        }
        half8 o;
        #pragma unroll
        for (int q = 0; q < 8; q++) o[q] = (f16)s[q];
        *(half8*)(&smbuf[r][cb]) = o;
    }
    __syncthreads();
    const int wv = threadIdx.x >> 6, lane = threadIdx.x & 63;
    const int c15 = lane & 15, kq = lane >> 4;

    { // f1: cols wv*32 + fn*16, fn<2
        f32x4 acc[2];
        acc[0] = (f32x4){0.f, 0.f, 0.f, 0.f}; acc[1] = acc[0];
        #pragma unroll
        for (int k0 = 0; k0 < 8; k0++) {
            half8 a = *(const half8*)(&smbuf[c15][k0 * 32 + kq * 8]);
            #pragma unroll
            for (int fn = 0; fn < 2; fn++) {
                half8 bv = *(const half8*)(f1w + (size_t)(wv * 32 + fn * 16 + c15) * 256 + k0 * 32 + kq * 8);
                acc[fn] = mfma16(a, bv, acc[fn]);
            }
        }
        #pragma unroll
        for (int fn = 0; fn < 2; fn++) {
            int col = wv * 32 + fn * 16 + c15;
            float bb = f1b[col];
            #pragma unroll
            for (int r = 0; r < 4; r++)
                f1buf[kq * 4 + r][col] = (f16)fmaxf(acc[fn][r] + bb, 0.f);
        }
    }
    __syncthreads();
    { // f2: cols wv*64 + fn*16, fn<4
        f32x4 acc[4];
        #pragma unroll
        for (int b = 0; b < 4; b++) acc[b] = (f32x4){0.f, 0.f, 0.f, 0.f};
        #pragma unroll
        for (int k0 = 0; k0 < 8; k0++) {
            half8 a = *(const half8*)(&f1buf[c15][k0 * 32 + kq * 8]);
            #pragma unroll
            for (int fn = 0; fn < 4; fn++) {
                half8 bv = *(const half8*)(f2w + (size_t)(wv * 64 + fn * 16 + c15) * 256 + k0 * 32 + kq * 8);
                acc[fn] = mfma16(a, bv, acc[fn]);
            }
        }
        #pragma unroll
        for (int fn = 0; fn < 4; fn++) {
            int col = wv * 64 + fn * 16 + c15;
            float bb = f2b[col];
            #pragma unroll
            for (int r = 0; r < 4; r++)
                f2buf[kq * 4 + r][col] = (f16)fmaxf(acc[fn][r] + bb, 0.f);
        }
    }
    __syncthreads();
    { // f3: cols wv*128 + fn*16, fn<8, N=1000 tail clamped
        f32x4 acc[8];
        #pragma unroll
        for (int b = 0; b < 8; b++) acc[b] = (f32x4){0.f, 0.f, 0.f, 0.f};
        #pragma unroll
        for (int k0 = 0; k0 < 16; k0++) {
            half8 a = *(const half8*)(&f2buf[c15][k0 * 32 + kq * 8]);
            #pragma unroll
            for (int fn = 0; fn < 8; fn++) {
                int col = wv * 128 + fn * 16 + c15;
                int cl = col < 1000 ? col : 999;
                half8 bv = *(const half8*)(f3w + (size_t)cl * 512 + k0 * 32 + kq * 8);
                acc[fn] = mfma16(a, bv, acc[fn]);
            }
        }
        #pragma unroll
        for (int fn = 0; fn < 8; fn++) {
            int col = wv * 128 + fn * 16 + c15;
            if (col < 1000) {
                float bb = f3b[col];
                #pragma unroll
                for (int r = 0; r < 4; r++)
                    out[(size_t)(b0 + kq * 4 + r) * 1000 + col] = acc[fn][r] + bb;
            }
        }
    }
}

// ---------------- launcher ----------------
extern "C" void kernel_launch(void* const* d_in, const int* in_sizes, int n_in,
                              void* d_out, int out_size, void* d_ws, size_t ws_size,
                              hipStream_t stream)
{
    if (ws_size < WS_NEED) return;
    const int* q_tok = (const int*)d_in[0];
    SfPtrs sf;
    for (int i = 0; i < 8; i++) sf.p[i] = (const int*)d_in[1 + i];
    const float* emb_f = (const float*)d_in[9];
    const float* qWih = (const float*)d_in[10];
    const float* qWhh = (const float*)d_in[11];
    const float* q_b  = (const float*)d_in[12];
    const float* sWih = (const float*)d_in[13];
    const float* sWhh = (const float*)d_in[14];
    const float* s_b  = (const float*)d_in[15];
    const float* g1W  = (const float*)d_in[16];
    const float* g1b  = (const float*)d_in[17];
    const float* g2W  = (const float*)d_in[18];
    const float* g2b  = (const float*)d_in[19];
    const float* g3W  = (const float*)d_in[20];
    const float* g3b  = (const float*)d_in[21];
    const float* g4W  = (const float*)d_in[22];
    const float* g4b  = (const float*)d_in[23];
    const float* f1W  = (const float*)d_in[24];
    const float* f1b  = (const float*)d_in[25];
    const float* f2W  = (const float*)d_in[26];
    const float* f2b  = (const float*)d_in[27];
    const float* f3W  = (const float*)d_in[28];
    const float* f3b  = (const float*)d_in[29];

    char* ws = (char*)d_ws;
    f16* emb_h = (f16*)(ws + OFF_EMB);
    f16* wqih  = (f16*)(ws + OFF_WQIH);
    f16* wqhh  = (f16*)(ws + OFF_WQHH);
    f16* wsih  = (f16*)(ws + OFF_WSIH);
    f16* wshh  = (f16*)(ws + OFF_WSHH);
    float* bq  = (float*)(ws + OFF_BQ);
    float* bs  = (float*)(ws + OFF_BS);
    f16* g1wp  = (f16*)(ws + OFF_G1WP);
    float* bias8 = (float*)(ws + OFF_BIAS8);
    f16* g2w = (f16*)(ws + OFF_G2W);
    f16* g3w = (f16*)(ws + OFF_G3W);
    f16* g4w = (f16*)(ws + OFF_G4W);
    f16* f1w = (f16*)(ws + OFF_F1W);
    f16* f2w = (f16*)(ws + OFF_F2W);
    f16* f3w = (f16*)(ws + OFF_F3W);
    f16* hs  = (f16*)(ws + OFF_HS);
    f16* hq  = (f16*)(ws + OFF_HQ);
    f16* act2 = (f16*)(ws + OFF_ACT2);

    CvtJobs cj;
    const float* srcs[7] = {emb_f, g2W, g3W, g4W, f1W, f2W, f3W};
    f16* dsts[7]         = {emb_h, g2w, g3w, g4w, f1w, f2w, f3w};
    int ns[7] = {1600000, 65536, 65536, 65536, 65536, 131072, 512000};
    for (int i = 0; i < 7; i++) { cj.src[i] = srcs[i]; cj.dst[i] = dsts[i]; cj.n[i] = ns[i]; }

    cvt_prep<<<dim3(782, 8), 256, 0, stream>>>(cj, g1W, g1b, g1wp, bias8,
                                               qWih, qWhh, q_b, sWih, sWhh, s_b,
                                               wqih, wqhh, bq, wsih, wshh, bs);
    lstm_kernel<<<1152, 64, 0, stream>>>(sf, q_tok, emb_h, wsih, wshh, bs, wqih, wqhh, bq, hs, hq);
    gemm_g1234<<<512, 512, 0, stream>>>(hs, hq, g1wp, bias8, g2w, g2b, g3w, g3b, g4w, g4b, act2);
    f123s_kernel<<<256, 512, 0, stream>>>(act2, f1w, f1b, f2w, f2b, f3w, f3b, (float*)d_out);
}

// Round 8
// 344.172 us; speedup vs baseline: 1.1451x; 1.1451x over previous
//
#include <hip/hip_runtime.h>
#include <stdint.h>
#include <stddef.h>

typedef __fp16 f16;
typedef __attribute__((ext_vector_type(8))) __fp16 half8;
typedef __attribute__((ext_vector_type(4))) __fp16 half4;
typedef __attribute__((ext_vector_type(4))) float f32x4;
typedef unsigned int u32;
typedef __attribute__((ext_vector_type(2))) u32 u32x2;
typedef __attribute__((ext_vector_type(4))) u32 u32x4;

static __device__ __forceinline__ f32x4 mfma16(half8 a, half8 b, f32x4 c) {
    return __builtin_amdgcn_mfma_f32_16x16x32_f16(a, b, c, 0, 0, 0);
}
static __device__ __forceinline__ float fexp2(float x) { float r; asm("v_exp_f32 %0, %1" : "=v"(r) : "v"(x)); return r; }
static __device__ __forceinline__ float frcp(float x)  { float r; asm("v_rcp_f32 %0, %1" : "=v"(r) : "v"(x)); return r; }

static constexpr float L2E  = 1.4426950408889634f;
static constexpr float L2E2 = 2.8853900817779268f;

static constexpr int LDA = 264;    // LDS row stride (f16): 8-way b128 groups = at the 1KB/wave floor
static constexpr int LDF2 = 520;

// ---------------- workspace layout (bytes) ----------------
static constexpr size_t OFF_EMB   = 0;
static constexpr size_t OFF_WQIH  = 3200000;
static constexpr size_t OFF_WQHH  = OFF_WQIH + 8192;
static constexpr size_t OFF_WSIH  = OFF_WQHH + 8192;
static constexpr size_t OFF_WSHH  = OFF_WSIH + 8192;
static constexpr size_t OFF_BQ    = OFF_WSHH + 8192;
static constexpr size_t OFF_BS    = OFF_BQ + 512;
static constexpr size_t OFF_G1WP  = OFF_BS + 512;
static constexpr size_t OFF_BIAS8 = OFF_G1WP + 32768;
static constexpr size_t OFF_G2W   = OFF_BIAS8 + 8192;
static constexpr size_t OFF_G3W   = OFF_G2W + 131072;
static constexpr size_t OFF_G4W   = OFF_G3W + 131072;
static constexpr size_t OFF_F1W   = OFF_G4W + 131072;
static constexpr size_t OFF_F2W   = OFF_F1W + 131072;
static constexpr size_t OFF_F3W   = OFF_F2W + 262144;
static constexpr size_t OFF_HS    = OFF_F3W + 1024000;
static constexpr size_t OFF_HQ    = OFF_HS + 2097152;
static constexpr size_t OFF_ACT2  = OFF_HQ + 262144;
static constexpr size_t WS_NEED   = OFF_ACT2 + 16777216;

// ---------------- fused fp32->fp16 conversion + small prep ----------------
struct CvtJobs { const float* src[7]; f16* dst[7]; int n[7]; };

__global__ __launch_bounds__(256) void cvt_prep(
    CvtJobs j,
    const float* __restrict__ g1W, const float* __restrict__ g1b,
    f16* __restrict__ wp, float* __restrict__ bias8,
    const float* __restrict__ qWih, const float* __restrict__ qWhh, const float* __restrict__ qb,
    const float* __restrict__ sWih, const float* __restrict__ sWhh, const float* __restrict__ sb,
    f16* __restrict__ wqih, f16* __restrict__ wqhh, float* __restrict__ bq,
    f16* __restrict__ wsih, f16* __restrict__ wshh, float* __restrict__ bs)
{
    int t = threadIdx.x;
    if (blockIdx.y < 7) {
        int jb = blockIdx.y;
        int i = (blockIdx.x * 256 + t) * 8;
        if (i >= j.n[jb]) return;
        const float* s = j.src[jb] + i;
        f32x4 a = *(const f32x4*)s;
        f32x4 b = *(const f32x4*)(s + 4);
        half8 o;
        o[0]=(f16)a[0]; o[1]=(f16)a[1]; o[2]=(f16)a[2]; o[3]=(f16)a[3];
        o[4]=(f16)b[0]; o[5]=(f16)b[1]; o[6]=(f16)b[2]; o[7]=(f16)b[3];
        *(half8*)(j.dst[jb] + i) = o;
        return;
    }
    if (blockIdx.x == 0) {
        int col = t;
        for (int k = 0; k < 64; k++) wp[col * 64 + k] = (f16)g1W[col * 65 + k];
        float wpos = g1W[col * 65 + 64];
        float b = g1b[col];
        for (int i = 0; i < 8; i++) bias8[i * 256 + col] = b + (float)i * wpos;
    } else if (blockIdx.x == 1) {
        for (int i = t; i < 4096; i += 256) {
            int row = i >> 5;
            float s = (row < 64 || row >= 96) ? -L2E : L2E2;
            wqih[i] = (f16)(qWih[i] * s);
            wqhh[i] = (f16)(qWhh[i] * s);
            wsih[i] = (f16)(sWih[i] * s);
            wshh[i] = (f16)(sWhh[i] * s);
        }
        if (t < 128) {
            float s = (t < 64 || t >= 96) ? -L2E : L2E2;
            bq[t] = qb[t] * s;
            bs[t] = sb[t] * s;
        }
    }
}

// ---------------- fused LSTM: 16 samples/wave, h exchanged via ds_bpermute ----------------
// Transposed-gate form: gates^T[128][16] = W * [x^T|h^T]; C col = lane&15 = sample,
// row = (lane>>4)*4 + r within 16-row tile n. Lane (c15,kq) produces h units
// jh*16+kq*4+r of sample c15 (hp[jh]); consumer lane (c15,kq) needs units kq*8..+7
// = hp[kq>>1] of lanes c15+32*(kq&1) and +16 -> 8 bpermute + 4 cndmask, no LDS.
struct SfPtrs { const int* p[8]; };

__global__ __launch_bounds__(64) void lstm_kernel(
    SfPtrs sf, const int* __restrict__ qtok, const f16* __restrict__ emb_h,
    const f16* __restrict__ wih_sf, const f16* __restrict__ whh_sf, const float* __restrict__ b_sf,
    const f16* __restrict__ wih_q,  const f16* __restrict__ whh_q,  const float* __restrict__ b_q,
    f16* __restrict__ hs_out, f16* __restrict__ hq_out)
{
    int lane = threadIdx.x;
    int c15 = lane & 15, kq = lane >> 4;
    int sbase = blockIdx.x * 16;
    bool isq = sbase >= 32768;
    const f16* wih = isq ? wih_q : wih_sf;
    const f16* whh = isq ? whh_q : whh_sf;
    const float* bvec = isq ? b_q : b_sf;

    half8 wi[8], wh[8];
    f32x4 bc[8];
    #pragma unroll
    for (int n = 0; n < 8; n++) {
        wi[n] = *(const half8*)(wih + (n * 16 + c15) * 32 + kq * 8);
        wh[n] = *(const half8*)(whh + (n * 16 + c15) * 32 + kq * 8);
        bc[n] = *(const f32x4*)(bvec + n * 16 + kq * 4);
    }
    int sg = sbase + c15;
    const int* tp;
    if (isq) tp = qtok + (sg - 32768) * 64;
    else     tp = sf.p[sg >> 12] + (sg & 4095) * 64;

    // bpermute byte-indices for the two source lanes of this lane's h-fragment
    int i1 = (c15 + ((kq & 1) << 5)) << 2;
    int i2 = i1 + 64;
    bool hi = kq >= 2;   // jh = kq>>1

    float cst[2][4] = {};
    half8 hf = {};       // h_0 = 0
    half8 xf = *(const half8*)(emb_h + (size_t)tp[0] * 32 + kq * 8);

    #pragma unroll 1
    for (int t = 0; t < 64; t++) {
        f32x4 acc[8];
        #pragma unroll
        for (int n = 0; n < 8; n++) acc[n] = mfma16(wi[n], xf, bc[n]);   // x-part (off critical path)
        #pragma unroll
        for (int n = 0; n < 8; n++) acc[n] = mfma16(wh[n], hf, acc[n]);  // recurrence
        if (t < 63) {
            int tk = tp[t + 1];
            xf = *(const half8*)(emb_h + (size_t)tk * 32 + kq * 8);
        }
        // gate math: acc_i/f/o = -log2e*gate, acc_g = +2log2e*gate (prescaled W,b)
        half4 hp0, hp1;
        #pragma unroll
        for (int jh = 0; jh < 2; jh++) {
            #pragma unroll
            for (int r = 0; r < 4; r++) {
                float ei = fexp2(acc[0 + jh][r]);
                float ef = fexp2(acc[2 + jh][r]);
                float eg = fexp2(acc[4 + jh][r]);
                float eo = fexp2(acc[6 + jh][r]);
                float t1 = 1.f + ei, t2 = 1.f + ef, t5 = 1.f + eo;
                float eg1 = eg + 1.f, egm = eg - 1.f;
                float t1e = t1 * eg1;
                float num = fmaf(egm, t2, cst[jh][r] * t1e);
                float cn  = num * frcp(t1e * t2);
                cst[jh][r] = cn;
                float ec  = fexp2(cn * L2E2);
                float hv  = (ec - 1.f) * frcp((ec + 1.f) * t5);
                if (jh == 0) hp0[r] = (f16)hv; else hp1[r] = (f16)hv;
            }
        }
        // in-register h exchange (within the 4 lanes sharing c15)
        u32x2 pa = __builtin_bit_cast(u32x2, hp0);
        u32x2 pb = __builtin_bit_cast(u32x2, hp1);
        int ra0 = __builtin_amdgcn_ds_bpermute(i1, (int)pa.x);
        int ra1 = __builtin_amdgcn_ds_bpermute(i1, (int)pa.y);
        int rb0 = __builtin_amdgcn_ds_bpermute(i1, (int)pb.x);
        int rb1 = __builtin_amdgcn_ds_bpermute(i1, (int)pb.y);
        int ra2 = __builtin_amdgcn_ds_bpermute(i2, (int)pa.x);
        int ra3 = __builtin_amdgcn_ds_bpermute(i2, (int)pa.y);
        int rb2 = __builtin_amdgcn_ds_bpermute(i2, (int)pb.x);
        int rb3 = __builtin_amdgcn_ds_bpermute(i2, (int)pb.y);
        u32x4 w;
        w.x = (u32)(hi ? rb0 : ra0);
        w.y = (u32)(hi ? rb1 : ra1);
        w.z = (u32)(hi ? rb2 : ra2);
        w.w = (u32)(hi ? rb3 : ra3);
        hf = __builtin_bit_cast(half8, w);
    }
    // hf now holds the final h fragment: units kq*8..+7 of sample c15
    if (isq) *(half8*)(hq_out + (size_t)(sg - 32768) * 32 + kq * 8) = hf;
    else     *(half8*)(hs_out + (size_t)sg * 32 + kq * 8) = hf;
}

// ---------------- fused g1..g4: 64-row strips, 8 waves (2 row x 4 col) ----------------
template<bool TOGLOBAL>
static __device__ __forceinline__ void layer256(
    const f16 (* __restrict__ src)[LDA], f16 (* __restrict__ dst)[LDA],
    const f16* __restrict__ W, const float* __restrict__ bias,
    f16* __restrict__ gout, int m0, int wm, int wn, int c15, int kq)
{
    f32x4 acc[2][4];
    #pragma unroll
    for (int a = 0; a < 2; a++)
        #pragma unroll
        for (int b = 0; b < 4; b++) acc[a][b] = (f32x4){0.f, 0.f, 0.f, 0.f};
    #pragma unroll
    for (int k0 = 0; k0 < 8; k0++) {
        half8 av[2], bv[4];
        #pragma unroll
        for (int fm = 0; fm < 2; fm++) av[fm] = *(const half8*)(&src[wm * 32 + fm * 16 + c15][k0 * 32 + kq * 8]);
        #pragma unroll
        for (int fn = 0; fn < 4; fn++) bv[fn] = *(const half8*)(W + (size_t)(wn * 64 + fn * 16 + c15) * 256 + k0 * 32 + kq * 8);
        #pragma unroll
        for (int fm = 0; fm < 2; fm++)
            #pragma unroll
            for (int fn = 0; fn < 4; fn++) acc[fm][fn] = mfma16(av[fm], bv[fn], acc[fm][fn]);
    }
    #pragma unroll
    for (int fn = 0; fn < 4; fn++) {
        int col = wn * 64 + fn * 16 + c15;
        float bb = bias[col];
        #pragma unroll
        for (int fm = 0; fm < 2; fm++)
            #pragma unroll
            for (int r = 0; r < 4; r++) {
                float v = fmaxf(acc[fm][fn][r] + bb, 0.f);
                int row = wm * 32 + fm * 16 + kq * 4 + r;
                if (TOGLOBAL) gout[(size_t)(m0 + row) * 256 + col] = (f16)v;
                else          dst[row][col] = (f16)v;
            }
    }
}

__global__ __launch_bounds__(512) void gemm_g1234(
    const f16* __restrict__ hs, const f16* __restrict__ hq,
    const f16* __restrict__ g1wp, const float* __restrict__ bias8,
    const f16* __restrict__ g2w, const float* __restrict__ g2b,
    const f16* __restrict__ g3w, const float* __restrict__ g3b,
    const f16* __restrict__ g4w, const float* __restrict__ g4b,
    f16* __restrict__ act2)
{
    __shared__ __align__(16) f16 actA[64][LDA];
    __shared__ __align__(16) f16 actB[64][LDA];
    const int wv = threadIdx.x >> 6, lane = threadIdx.x & 63;
    const int c15 = lane & 15, kq = lane >> 4;
    const int wm = wv >> 2, wn = wv & 3;
    const int m0 = blockIdx.x * 64;
    const float* brow = bias8 + ((m0 >> 12) << 8);

    { // g1: K=64 (hs || hq)
        f32x4 acc[2][4];
        #pragma unroll
        for (int a = 0; a < 2; a++)
            #pragma unroll
            for (int b = 0; b < 4; b++) acc[a][b] = (f32x4){0.f, 0.f, 0.f, 0.f};
        half8 av[2], bv[4];
        #pragma unroll
        for (int fm = 0; fm < 2; fm++) av[fm] = *(const half8*)(hs + (size_t)(m0 + wm * 32 + fm * 16 + c15) * 32 + kq * 8);
        #pragma unroll
        for (int fn = 0; fn < 4; fn++) bv[fn] = *(const half8*)(g1wp + (size_t)(wn * 64 + fn * 16 + c15) * 64 + kq * 8);
        #pragma unroll
        for (int fm = 0; fm < 2; fm++)
            #pragma unroll
            for (int fn = 0; fn < 4; fn++) acc[fm][fn] = mfma16(av[fm], bv[fn], acc[fm][fn]);
        #pragma unroll
        for (int fm = 0; fm < 2; fm++) av[fm] = *(const half8*)(hq + (size_t)((m0 + wm * 32 + fm * 16 + c15) & 4095) * 32 + kq * 8);
        #pragma unroll
        for (int fn = 0; fn < 4; fn++) bv[fn] = *(const half8*)(g1wp + (size_t)(wn * 64 + fn * 16 + c15) * 64 + 32 + kq * 8);
        #pragma unroll
        for (int fm = 0; fm < 2; fm++)
            #pragma unroll
            for (int fn = 0; fn < 4; fn++) acc[fm][fn] = mfma16(av[fm], bv[fn], acc[fm][fn]);
        #pragma unroll
        for (int fn = 0; fn < 4; fn++) {
            int col = wn * 64 + fn * 16 + c15;
            float bb = brow[col];
            #pragma unroll
            for (int fm = 0; fm < 2; fm++)
                #pragma unroll
                for (int r = 0; r < 4; r++)
                    actA[wm * 32 + fm * 16 + kq * 4 + r][col] = (f16)fmaxf(acc[fm][fn][r] + bb, 0.f);
        }
    }
    __syncthreads();
    layer256<false>(actA, actB, g2w, g2b, nullptr, m0, wm, wn, c15, kq);
    __syncthreads();
    layer256<false>(actB, actA, g3w, g3b, nullptr, m0, wm, wn, c15, kq);
    __syncthreads();
    layer256<true>(actA, actB, g4w, g4b, act2, m0, wm, wn, c15, kq);
}

// ---------------- fused sum8 + f1 + f2 + f3: 16-row strips, 8 waves ----------------
__global__ __launch_bounds__(512) void f123s_kernel(
    const f16* __restrict__ act2,
    const f16* __restrict__ f1w, const float* __restrict__ f1b,
    const f16* __restrict__ f2w, const float* __restrict__ f2b,
    const f16* __restrict__ f3w, const float* __restrict__ f3b,
    float* __restrict__ out)
{
    __shared__ __align__(16) f16 smbuf[16][LDA];
    __shared__ __align__(16) f16 f1buf[16][LDA];
    __shared__ __align__(16) f16 f2buf[16][LDF2];
    const int b0 = blockIdx.x * 16;

    { // segment-sum over 8 relations
        int r = threadIdx.x >> 5, cb = (threadIdx.x & 31) * 8;
        float s[8] = {};
        #pragma unroll
        for (int i = 0; i < 8; i++) {
            half8 v = *(const half8*)(act2 + ((size_t)(i * 4096 + b0 + r)) * 256 + cb);
            #pragma unroll
            for (int q = 0; q < 8; q++) s[q] += (float)v[q];
        }
        half8 o;
        #pragma unroll
        for (int q = 0; q < 8; q++) o[q] = (f16)s[q];
        *(half8*)(&smbuf[r][cb]) = o;
    }
    __syncthreads();
    const int wv = threadIdx.x >> 6, lane = threadIdx.x & 63;
    const int c15 = lane & 15, kq = lane >> 4;

    { // f1
        f32x4 acc[2];
        acc[0] = (f32x4){0.f, 0.f, 0.f, 0.f}; acc[1] = acc[0];
        #pragma unroll
        for (int k0 = 0; k0 < 8; k0++) {
            half8 a = *(const half8*)(&smbuf[c15][k0 * 32 + kq * 8]);
            #pragma unroll
            for (int fn = 0; fn < 2; fn++) {
                half8 bv = *(const half8*)(f1w + (size_t)(wv * 32 + fn * 16 + c15) * 256 + k0 * 32 + kq * 8);
                acc[fn] = mfma16(a, bv, acc[fn]);
            }
        }
        #pragma unroll
        for (int fn = 0; fn < 2; fn++) {
            int col = wv * 32 + fn * 16 + c15;
            float bb = f1b[col];
            #pragma unroll
            for (int r = 0; r < 4; r++)
                f1buf[kq * 4 + r][col] = (f16)fmaxf(acc[fn][r] + bb, 0.f);
        }
    }
    __syncthreads();
    { // f2
        f32x4 acc[4];
        #pragma unroll
        for (int b = 0; b < 4; b++) acc[b] = (f32x4){0.f, 0.f, 0.f, 0.f};
        #pragma unroll
        for (int k0 = 0; k0 < 8; k0++) {
            half8 a = *(const half8*)(&f1buf[c15][k0 * 32 + kq * 8]);
            #pragma unroll
            for (int fn = 0; fn < 4; fn++) {
                half8 bv = *(const half8*)(f2w + (size_t)(wv * 64 + fn * 16 + c15) * 256 + k0 * 32 + kq * 8);
                acc[fn] = mfma16(a, bv, acc[fn]);
            }
        }
        #pragma unroll
        for (int fn = 0; fn < 4; fn++) {
            int col = wv * 64 + fn * 16 + c15;
            float bb = f2b[col];
            #pragma unroll
            for (int r = 0; r < 4; r++)
                f2buf[kq * 4 + r][col] = (f16)fmaxf(acc[fn][r] + bb, 0.f);
        }
    }
    __syncthreads();
    { // f3
        f32x4 acc[8];
        #pragma unroll
        for (int b = 0; b < 8; b++) acc[b] = (f32x4){0.f, 0.f, 0.f, 0.f};
        #pragma unroll
        for (int k0 = 0; k0 < 16; k0++) {
            half8 a = *(const half8*)(&f2buf[c15][k0 * 32 + kq * 8]);
            #pragma unroll
            for (int fn = 0; fn < 8; fn++) {
                int col = wv * 128 + fn * 16 + c15;
                int cl = col < 1000 ? col : 999;
                half8 bv = *(const half8*)(f3w + (size_t)cl * 512 + k0 * 32 + kq * 8);
                acc[fn] = mfma16(a, bv, acc[fn]);
            }
        }
        #pragma unroll
        for (int fn = 0; fn < 8; fn++) {
            int col = wv * 128 + fn * 16 + c15;
            if (col < 1000) {
                float bb = f3b[col];
                #pragma unroll
                for (int r = 0; r < 4; r++)
                    out[(size_t)(b0 + kq * 4 + r) * 1000 + col] = acc[fn][r] + bb;
            }
        }
    }
}

// ---------------- launcher ----------------
extern "C" void kernel_launch(void* const* d_in, const int* in_sizes, int n_in,
                              void* d_out, int out_size, void* d_ws, size_t ws_size,
                              hipStream_t stream)
{
    if (ws_size < WS_NEED) return;
    const int* q_tok = (const int*)d_in[0];
    SfPtrs sf;
    for (int i = 0; i < 8; i++) sf.p[i] = (const int*)d_in[1 + i];
    const float* emb_f = (const float*)d_in[9];
    const float* qWih = (const float*)d_in[10];
    const float* qWhh = (const float*)d_in[11];
    const float* q_b  = (const float*)d_in[12];
    const float* sWih = (const float*)d_in[13];
    const float* sWhh = (const float*)d_in[14];
    const float* s_b  = (const float*)d_in[15];
    const float* g1W  = (const float*)d_in[16];
    const float* g1b  = (const float*)d_in[17];
    const float* g2W  = (const float*)d_in[18];
    const float* g2b  = (const float*)d_in[19];
    const float* g3W  = (const float*)d_in[20];
    const float* g3b  = (const float*)d_in[21];
    const float* g4W  = (const float*)d_in[22];
    const float* g4b  = (const float*)d_in[23];
    const float* f1W  = (const float*)d_in[24];
    const float* f1b  = (const float*)d_in[25];
    const float* f2W  = (const float*)d_in[26];
    const float* f2b  = (const float*)d_in[27];
    const float* f3W  = (const float*)d_in[28];
    const float* f3b  = (const float*)d_in[29];

    char* ws = (char*)d_ws;
    f16* emb_h = (f16*)(ws + OFF_EMB);
    f16* wqih  = (f16*)(ws + OFF_WQIH);
    f16* wqhh  = (f16*)(ws + OFF_WQHH);
    f16* wsih  = (f16*)(ws + OFF_WSIH);
    f16* wshh  = (f16*)(ws + OFF_WSHH);
    float* bq  = (float*)(ws + OFF_BQ);
    float* bs  = (float*)(ws + OFF_BS);
    f16* g1wp  = (f16*)(ws + OFF_G1WP);
    float* bias8 = (float*)(ws + OFF_BIAS8);
    f16* g2w = (f16*)(ws + OFF_G2W);
    f16* g3w = (f16*)(ws + OFF_G3W);
    f16* g4w = (f16*)(ws + OFF_G4W);
    f16* f1w = (f16*)(ws + OFF_F1W);
    f16* f2w = (f16*)(ws + OFF_F2W);
    f16* f3w = (f16*)(ws + OFF_F3W);
    f16* hs  = (f16*)(ws + OFF_HS);
    f16* hq  = (f16*)(ws + OFF_HQ);
    f16* act2 = (f16*)(ws + OFF_ACT2);

    CvtJobs cj;
    const float* srcs[7] = {emb_f, g2W, g3W, g4W, f1W, f2W, f3W};
    f16* dsts[7]         = {emb_h, g2w, g3w, g4w, f1w, f2w, f3w};
    int ns[7] = {1600000, 65536, 65536, 65536, 65536, 131072, 512000};
    for (int i = 0; i < 7; i++) { cj.src[i] = srcs[i]; cj.dst[i] = dsts[i]; cj.n[i] = ns[i]; }

    cvt_prep<<<dim3(782, 8), 256, 0, stream>>>(cj, g1W, g1b, g1wp, bias8,
                                               qWih, qWhh, q_b, sWih, sWhh, s_b,
                                               wqih, wqhh, bq, wsih, wshh, bs);
    lstm_kernel<<<2304, 64, 0, stream>>>(sf, q_tok, emb_h, wsih, wshh, bs, wqih, wqhh, bq, hs, hq);
    gemm_g1234<<<512, 512, 0, stream>>>(hs, hq, g1wp, bias8, g2w, g2b, g3w, g3b, g4w, g4b, act2);
    f123s_kernel<<<256, 512, 0, stream>>>(act2, f1w, f1b, f2w, f2b, f3w, f3b, (float*)d_out);
}

// Round 9
// 319.464 us; speedup vs baseline: 1.2336x; 1.0773x over previous
//
#include <hip/hip_runtime.h>
#include <stdint.h>
#include <stddef.h>

typedef __fp16 f16;
typedef __attribute__((ext_vector_type(8))) __fp16 half8;
typedef __attribute__((ext_vector_type(4))) __fp16 half4;
typedef __attribute__((ext_vector_type(4))) float f32x4;
typedef unsigned int u32;

static __device__ __forceinline__ f32x4 mfma16(half8 a, half8 b, f32x4 c) {
    return __builtin_amdgcn_mfma_f32_16x16x32_f16(a, b, c, 0, 0, 0);
}
static __device__ __forceinline__ float fexp2(float x) { float r; asm("v_exp_f32 %0, %1" : "=v"(r) : "v"(x)); return r; }
static __device__ __forceinline__ float frcp(float x)  { float r; asm("v_rcp_f32 %0, %1" : "=v"(r) : "v"(x)); return r; }

static constexpr float L2E  = 1.4426950408889634f;
static constexpr float L2E2 = 2.8853900817779268f;

static constexpr int LDA = 264;    // LDS row stride (f16)
static constexpr int LDF2 = 520;

// ---------------- workspace layout (bytes) ----------------
static constexpr size_t OFF_EMB   = 0;
static constexpr size_t OFF_WQIH  = 3200000;
static constexpr size_t OFF_WQHH  = OFF_WQIH + 8192;
static constexpr size_t OFF_WSIH  = OFF_WQHH + 8192;
static constexpr size_t OFF_WSHH  = OFF_WSIH + 8192;
static constexpr size_t OFF_BQ    = OFF_WSHH + 8192;
static constexpr size_t OFF_BS    = OFF_BQ + 512;
static constexpr size_t OFF_G1WP  = OFF_BS + 512;
static constexpr size_t OFF_BIAS8 = OFF_G1WP + 32768;
static constexpr size_t OFF_G2W   = OFF_BIAS8 + 8192;
static constexpr size_t OFF_G3W   = OFF_G2W + 131072;
static constexpr size_t OFF_G4W   = OFF_G3W + 131072;
static constexpr size_t OFF_F1W   = OFF_G4W + 131072;
static constexpr size_t OFF_F2W   = OFF_F1W + 131072;
static constexpr size_t OFF_F3W   = OFF_F2W + 262144;
static constexpr size_t OFF_HS    = OFF_F3W + 1024000;
static constexpr size_t OFF_HQ    = OFF_HS + 2097152;
static constexpr size_t OFF_ACT2  = OFF_HQ + 262144;
static constexpr size_t WS_NEED   = OFF_ACT2 + 16777216;

// ---------------- fused fp32->fp16 conversion + small prep ----------------
struct CvtJobs { const float* src[7]; f16* dst[7]; int n[7]; };

__global__ __launch_bounds__(256) void cvt_prep(
    CvtJobs j,
    const float* __restrict__ g1W, const float* __restrict__ g1b,
    f16* __restrict__ wp, float* __restrict__ bias8,
    const float* __restrict__ qWih, const float* __restrict__ qWhh, const float* __restrict__ qb,
    const float* __restrict__ sWih, const float* __restrict__ sWhh, const float* __restrict__ sb,
    f16* __restrict__ wqih, f16* __restrict__ wqhh, float* __restrict__ bq,
    f16* __restrict__ wsih, f16* __restrict__ wshh, float* __restrict__ bs)
{
    int t = threadIdx.x;
    if (blockIdx.y < 7) {
        int jb = blockIdx.y;
        int i = (blockIdx.x * 256 + t) * 8;
        if (i >= j.n[jb]) return;
        const float* s = j.src[jb] + i;
        f32x4 a = *(const f32x4*)s;
        f32x4 b = *(const f32x4*)(s + 4);
        half8 o;
        o[0]=(f16)a[0]; o[1]=(f16)a[1]; o[2]=(f16)a[2]; o[3]=(f16)a[3];
        o[4]=(f16)b[0]; o[5]=(f16)b[1]; o[6]=(f16)b[2]; o[7]=(f16)b[3];
        *(half8*)(j.dst[jb] + i) = o;
        return;
    }
    if (blockIdx.x == 0) {
        int col = t;
        for (int k = 0; k < 64; k++) wp[col * 64 + k] = (f16)g1W[col * 65 + k];
        float wpos = g1W[col * 65 + 64];
        float b = g1b[col];
        for (int i = 0; i < 8; i++) bias8[i * 256 + col] = b + (float)i * wpos;
    } else if (blockIdx.x == 1) {
        for (int i = t; i < 4096; i += 256) {
            int row = i >> 5;
            float s = (row < 64 || row >= 96) ? -L2E : L2E2;
            wqih[i] = (f16)(qWih[i] * s);
            wqhh[i] = (f16)(qWhh[i] * s);
            wsih[i] = (f16)(sWih[i] * s);
            wshh[i] = (f16)(sWhh[i] * s);
        }
        if (t < 128) {
            float s = (t < 64 || t >= 96) ? -L2E : L2E2;
            bq[t] = qb[t] * s;
            bs[t] = sb[t] * s;
        }
    }
}

// ---------------- fused LSTM: 16 samples per 2-wave block ----------------
// Wave w owns hidden units w*16..w*16+15 (gate-row tiles {w,2+w,4+w,6+w}).
// Per step: 4 wi-MFMA + 4 wh-MFMA, gate math for 4 units/lane, write h-half
// to LDS double-buffer, one __syncthreads, flip. 4608 waves = 4.5/SIMD.
struct SfPtrs { const int* p[8]; };

__global__ __launch_bounds__(128) void lstm_kernel(
    SfPtrs sf, const int* __restrict__ qtok, const f16* __restrict__ emb_h,
    const f16* __restrict__ wih_sf, const f16* __restrict__ whh_sf, const float* __restrict__ b_sf,
    const f16* __restrict__ wih_q,  const f16* __restrict__ whh_q,  const float* __restrict__ b_q,
    f16* __restrict__ hs_out, f16* __restrict__ hq_out)
{
    __shared__ __align__(16) char hbuf[2][16 * 80];   // h[sample][unit], 80B row stride
    int tid = threadIdx.x;
    int w = tid >> 6, lane = tid & 63;
    int c15 = lane & 15, kq = lane >> 4;
    int sbase = blockIdx.x * 16;
    bool isq = sbase >= 32768;
    const f16* wih = isq ? wih_q : wih_sf;
    const f16* whh = isq ? whh_q : whh_sf;
    const float* bvec = isq ? b_q : b_sf;

    // weight fragments for this wave's 4 gate tiles (i,f,g,o of units w*16..+15)
    half8 wi[4], wh[4];
    f32x4 bc[4];
    #pragma unroll
    for (int jg = 0; jg < 4; jg++) {
        int row = (2 * jg + w) * 16 + c15;
        wi[jg] = *(const half8*)(wih + row * 32 + kq * 8);
        wh[jg] = *(const half8*)(whh + row * 32 + kq * 8);
        bc[jg] = *(const f32x4*)(bvec + (2 * jg + w) * 16 + kq * 4);
    }
    int sg = sbase + c15;
    const int* tp;
    if (isq) tp = qtok + (sg - 32768) * 64;
    else     tp = sf.p[sg >> 12] + (sg & 4095) * 64;

    // zero both h buffers (2 x 1280 B = 640 dwords)
    for (int i = tid; i < 640; i += 128) ((u32*)hbuf[0])[i] = 0;
    __syncthreads();

    float cst[4] = {};
    int rb = 0;
    const int hoff_r = c15 * 80 + kq * 16;            // b128 read: units kq*8..+7 of sample c15
    const int hoff_w = c15 * 80 + w * 32 + kq * 8;    // b64 write: units w*16+kq*4..+3

    half8 xf = *(const half8*)(emb_h + (size_t)tp[0] * 32 + kq * 8);

    #pragma unroll 1
    for (int t = 0; t < 64; t++) {
        half8 hf = *(const half8*)(hbuf[rb] + hoff_r);
        f32x4 acc[4];
        #pragma unroll
        for (int jg = 0; jg < 4; jg++) acc[jg] = mfma16(wi[jg], xf, bc[jg]);
        #pragma unroll
        for (int jg = 0; jg < 4; jg++) acc[jg] = mfma16(wh[jg], hf, acc[jg]);
        if (t < 63) {
            int tk = tp[t + 1];
            xf = *(const half8*)(emb_h + (size_t)tk * 32 + kq * 8);
        }
        // acc[0]=-l2e*i, acc[1]=-l2e*f, acc[2]=+2l2e*g, acc[3]=-l2e*o (prescaled W,b)
        half4 hp;
        #pragma unroll
        for (int r = 0; r < 4; r++) {
            float ei = fexp2(acc[0][r]);
            float ef = fexp2(acc[1][r]);
            float eg = fexp2(acc[2][r]);
            float eo = fexp2(acc[3][r]);
            float t1 = 1.f + ei, t2 = 1.f + ef, t5 = 1.f + eo;
            float eg1 = eg + 1.f, egm = eg - 1.f;
            float t1e = t1 * eg1;
            float num = fmaf(egm, t2, cst[r] * t1e);
            float cn  = num * frcp(t1e * t2);
            cst[r] = cn;
            float ec  = fexp2(cn * L2E2);
            hp[r] = (f16)((ec - 1.f) * frcp((ec + 1.f) * t5));
        }
        *(half4*)(hbuf[rb ^ 1] + hoff_w) = hp;
        __syncthreads();   // writes of step t visible; reads of buf[rb] all done
        rb ^= 1;
    }
    // final h is in hbuf[rb]; wave 0 stores all 32 units (b128 per lane)
    if (w == 0) {
        half8 hv = *(const half8*)(hbuf[rb] + hoff_r);
        if (isq) *(half8*)(hq_out + (size_t)(sg - 32768) * 32 + kq * 8) = hv;
        else     *(half8*)(hs_out + (size_t)sg * 32 + kq * 8) = hv;
    }
}

// ---------------- fused g1..g4: 64-row strips, 8 waves (2 row x 4 col) ----------------
template<bool TOGLOBAL>
static __device__ __forceinline__ void layer256(
    const f16 (* __restrict__ src)[LDA], f16 (* __restrict__ dst)[LDA],
    const f16* __restrict__ W, const float* __restrict__ bias,
    f16* __restrict__ gout, int m0, int wm, int wn, int c15, int kq)
{
    f32x4 acc[2][4];
    #pragma unroll
    for (int a = 0; a < 2; a++)
        #pragma unroll
        for (int b = 0; b < 4; b++) acc[a][b] = (f32x4){0.f, 0.f, 0.f, 0.f};
    #pragma unroll
    for (int k0 = 0; k0 < 8; k0++) {
        half8 av[2], bv[4];
        #pragma unroll
        for (int fm = 0; fm < 2; fm++) av[fm] = *(const half8*)(&src[wm * 32 + fm * 16 + c15][k0 * 32 + kq * 8]);
        #pragma unroll
        for (int fn = 0; fn < 4; fn++) bv[fn] = *(const half8*)(W + (size_t)(wn * 64 + fn * 16 + c15) * 256 + k0 * 32 + kq * 8);
        #pragma unroll
        for (int fm = 0; fm < 2; fm++)
            #pragma unroll
            for (int fn = 0; fn < 4; fn++) acc[fm][fn] = mfma16(av[fm], bv[fn], acc[fm][fn]);
    }
    #pragma unroll
    for (int fn = 0; fn < 4; fn++) {
        int col = wn * 64 + fn * 16 + c15;
        float bb = bias[col];
        #pragma unroll
        for (int fm = 0; fm < 2; fm++)
            #pragma unroll
            for (int r = 0; r < 4; r++) {
                float v = fmaxf(acc[fm][fn][r] + bb, 0.f);
                int row = wm * 32 + fm * 16 + kq * 4 + r;
                if (TOGLOBAL) gout[(size_t)(m0 + row) * 256 + col] = (f16)v;
                else          dst[row][col] = (f16)v;
            }
    }
}

__global__ __launch_bounds__(512) void gemm_g1234(
    const f16* __restrict__ hs, const f16* __restrict__ hq,
    const f16* __restrict__ g1wp, const float* __restrict__ bias8,
    const f16* __restrict__ g2w, const float* __restrict__ g2b,
    const f16* __restrict__ g3w, const float* __restrict__ g3b,
    const f16* __restrict__ g4w, const float* __restrict__ g4b,
    f16* __restrict__ act2)
{
    __shared__ __align__(16) f16 actA[64][LDA];
    __shared__ __align__(16) f16 actB[64][LDA];
    const int wv = threadIdx.x >> 6, lane = threadIdx.x & 63;
    const int c15 = lane & 15, kq = lane >> 4;
    const int wm = wv >> 2, wn = wv & 3;
    const int m0 = blockIdx.x * 64;
    const float* brow = bias8 + ((m0 >> 12) << 8);

    { // g1: K=64 (hs || hq)
        f32x4 acc[2][4];
        #pragma unroll
        for (int a = 0; a < 2; a++)
            #pragma unroll
            for (int b = 0; b < 4; b++) acc[a][b] = (f32x4){0.f, 0.f, 0.f, 0.f};
        half8 av[2], bv[4];
        #pragma unroll
        for (int fm = 0; fm < 2; fm++) av[fm] = *(const half8*)(hs + (size_t)(m0 + wm * 32 + fm * 16 + c15) * 32 + kq * 8);
        #pragma unroll
        for (int fn = 0; fn < 4; fn++) bv[fn] = *(const half8*)(g1wp + (size_t)(wn * 64 + fn * 16 + c15) * 64 + kq * 8);
        #pragma unroll
        for (int fm = 0; fm < 2; fm++)
            #pragma unroll
            for (int fn = 0; fn < 4; fn++) acc[fm][fn] = mfma16(av[fm], bv[fn], acc[fm][fn]);
        #pragma unroll
        for (int fm = 0; fm < 2; fm++) av[fm] = *(const half8*)(hq + (size_t)((m0 + wm * 32 + fm * 16 + c15) & 4095) * 32 + kq * 8);
        #pragma unroll
        for (int fn = 0; fn < 4; fn++) bv[fn] = *(const half8*)(g1wp + (size_t)(wn * 64 + fn * 16 + c15) * 64 + 32 + kq * 8);
        #pragma unroll
        for (int fm = 0; fm < 2; fm++)
            #pragma unroll
            for (int fn = 0; fn < 4; fn++) acc[fm][fn] = mfma16(av[fm], bv[fn], acc[fm][fn]);
        #pragma unroll
        for (int fn = 0; fn < 4; fn++) {
            int col = wn * 64 + fn * 16 + c15;
            float bb = brow[col];
            #pragma unroll
            for (int fm = 0; fm < 2; fm++)
                #pragma unroll
                for (int r = 0; r < 4; r++)
                    actA[wm * 32 + fm * 16 + kq * 4 + r][col] = (f16)fmaxf(acc[fm][fn][r] + bb, 0.f);
        }
    }
    __syncthreads();
    layer256<false>(actA, actB, g2w, g2b, nullptr, m0, wm, wn, c15, kq);
    __syncthreads();
    layer256<false>(actB, actA, g3w, g3b, nullptr, m0, wm, wn, c15, kq);
    __syncthreads();
    layer256<true>(actA, actB, g4w, g4b, act2, m0, wm, wn, c15, kq);
}

// ---------------- fused sum8 + f1 + f2 + f3: 16-row strips, 8 waves ----------------
__global__ __launch_bounds__(512) void f123s_kernel(
    const f16* __restrict__ act2,
    const f16* __restrict__ f1w, const float* __restrict__ f1b,
    const f16* __restrict__ f2w, const float* __restrict__ f2b,
    const f16* __restrict__ f3w, const float* __restrict__ f3b,
    float* __restrict__ out)
{
    __shared__ __align__(16) f16 smbuf[16][LDA];
    __shared__ __align__(16) f16 f1buf[16][LDA];
    __shared__ __align__(16) f16 f2buf[16][LDF2];
    const int b0 = blockIdx.x * 16;

    { // segment-sum over 8 relations
        int r = threadIdx.x >> 5, cb = (threadIdx.x & 31) * 8;
        float s[8] = {};
        #pragma unroll
        for (int i = 0; i < 8; i++) {
            half8 v = *(const half8*)(act2 + ((size_t)(i * 4096 + b0 + r)) * 256 + cb);
            #pragma unroll
            for (int q = 0; q < 8; q++) s[q] += (float)v[q];
        }
        half8 o;
        #pragma unroll
        for (int q = 0; q < 8; q++) o[q] = (f16)s[q];
        *(half8*)(&smbuf[r][cb]) = o;
    }
    __syncthreads();
    const int wv = threadIdx.x >> 6, lane = threadIdx.x & 63;
    const int c15 = lane & 15, kq = lane >> 4;

    { // f1
        f32x4 acc[2];
        acc[0] = (f32x4){0.f, 0.f, 0.f, 0.f}; acc[1] = acc[0];
        #pragma unroll
        for (int k0 = 0; k0 < 8; k0++) {
            half8 a = *(const half8*)(&smbuf[c15][k0 * 32 + kq * 8]);
            #pragma unroll
            for (int fn = 0; fn < 2; fn++) {
                half8 bv = *(const half8*)(f1w + (size_t)(wv * 32 + fn * 16 + c15) * 256 + k0 * 32 + kq * 8);
                acc[fn] = mfma16(a, bv, acc[fn]);
            }
        }
        #pragma unroll
        for (int fn = 0; fn < 2; fn++) {
            int col = wv * 32 + fn * 16 + c15;
            float bb = f1b[col];
            #pragma unroll
            for (int r = 0; r < 4; r++)
                f1buf[kq * 4 + r][col] = (f16)fmaxf(acc[fn][r] + bb, 0.f);
        }
    }
    __syncthreads();
    { // f2
        f32x4 acc[4];
        #pragma unroll
        for (int b = 0; b < 4; b++) acc[b] = (f32x4){0.f, 0.f, 0.f, 0.f};
        #pragma unroll
        for (int k0 = 0; k0 < 8; k0++) {
            half8 a = *(const half8*)(&f1buf[c15][k0 * 32 + kq * 8]);
            #pragma unroll
            for (int fn = 0; fn < 4; fn++) {
                half8 bv = *(const half8*)(f2w + (size_t)(wv * 64 + fn * 16 + c15) * 256 + k0 * 32 + kq * 8);
                acc[fn] = mfma16(a, bv, acc[fn]);
            }
        }
        #pragma unroll
        for (int fn = 0; fn < 4; fn++) {
            int col = wv * 64 + fn * 16 + c15;
            float bb = f2b[col];
            #pragma unroll
            for (int r = 0; r < 4; r++)
                f2buf[kq * 4 + r][col] = (f16)fmaxf(acc[fn][r] + bb, 0.f);
        }
    }
    __syncthreads();
    { // f3
        f32x4 acc[8];
        #pragma unroll
        for (int b = 0; b < 8; b++) acc[b] = (f32x4){0.f, 0.f, 0.f, 0.f};
        #pragma unroll
        for (int k0 = 0; k0 < 16; k0++) {
            half8 a = *(const half8*)(&f2buf[c15][k0 * 32 + kq * 8]);
            #pragma unroll
            for (int fn = 0; fn < 8; fn++) {
                int col = wv * 128 + fn * 16 + c15;
                int cl = col < 1000 ? col : 999;
                half8 bv = *(const half8*)(f3w + (size_t)cl * 512 + k0 * 32 + kq * 8);
                acc[fn] = mfma16(a, bv, acc[fn]);
            }
        }
        #pragma unroll
        for (int fn = 0; fn < 8; fn++) {
            int col = wv * 128 + fn * 16 + c15;
            if (col < 1000) {
                float bb = f3b[col];
                #pragma unroll
                for (int r = 0; r < 4; r++)
                    out[(size_t)(b0 + kq * 4 + r) * 1000 + col] = acc[fn][r] + bb;
            }
        }
    }
}

// ---------------- launcher ----------------
extern "C" void kernel_launch(void* const* d_in, const int* in_sizes, int n_in,
                              void* d_out, int out_size, void* d_ws, size_t ws_size,
                              hipStream_t stream)
{
    if (ws_size < WS_NEED) return;
    const int* q_tok = (const int*)d_in[0];
    SfPtrs sf;
    for (int i = 0; i < 8; i++) sf.p[i] = (const int*)d_in[1 + i];
    const float* emb_f = (const float*)d_in[9];
    const float* qWih = (const float*)d_in[10];
    const float* qWhh = (const float*)d_in[11];
    const float* q_b  = (const float*)d_in[12];
    const float* sWih = (const float*)d_in[13];
    const float* sWhh = (const float*)d_in[14];
    const float* s_b  = (const float*)d_in[15];
    const float* g1W  = (const float*)d_in[16];
    const float* g1b  = (const float*)d_in[17];
    const float* g2W  = (const float*)d_in[18];
    const float* g2b  = (const float*)d_in[19];
    const float* g3W  = (const float*)d_in[20];
    const float* g3b  = (const float*)d_in[21];
    const float* g4W  = (const float*)d_in[22];
    const float* g4b  = (const float*)d_in[23];
    const float* f1W  = (const float*)d_in[24];
    const float* f1b  = (const float*)d_in[25];
    const float* f2W  = (const float*)d_in[26];
    const float* f2b  = (const float*)d_in[27];
    const float* f3W  = (const float*)d_in[28];
    const float* f3b  = (const float*)d_in[29];

    char* ws = (char*)d_ws;
    f16* emb_h = (f16*)(ws + OFF_EMB);
    f16* wqih  = (f16*)(ws + OFF_WQIH);
    f16* wqhh  = (f16*)(ws + OFF_WQHH);
    f16* wsih  = (f16*)(ws + OFF_WSIH);
    f16* wshh  = (f16*)(ws + OFF_WSHH);
    float* bq  = (float*)(ws + OFF_BQ);
    float* bs  = (float*)(ws + OFF_BS);
    f16* g1wp  = (f16*)(ws + OFF_G1WP);
    float* bias8 = (float*)(ws + OFF_BIAS8);
    f16* g2w = (f16*)(ws + OFF_G2W);
    f16* g3w = (f16*)(ws + OFF_G3W);
    f16* g4w = (f16*)(ws + OFF_G4W);
    f16* f1w = (f16*)(ws + OFF_F1W);
    f16* f2w = (f16*)(ws + OFF_F2W);
    f16* f3w = (f16*)(ws + OFF_F3W);
    f16* hs  = (f16*)(ws + OFF_HS);
    f16* hq  = (f16*)(ws + OFF_HQ);
    f16* act2 = (f16*)(ws + OFF_ACT2);

    CvtJobs cj;
    const float* srcs[7] = {emb_f, g2W, g3W, g4W, f1W, f2W, f3W};
    f16* dsts[7]         = {emb_h, g2w, g3w, g4w, f1w, f2w, f3w};
    int ns[7] = {1600000, 65536, 65536, 65536, 65536, 131072, 512000};
    for (int i = 0; i < 7; i++) { cj.src[i] = srcs[i]; cj.dst[i] = dsts[i]; cj.n[i] = ns[i]; }

    cvt_prep<<<dim3(782, 8), 256, 0, stream>>>(cj, g1W, g1b, g1wp, bias8,
                                               qWih, qWhh, q_b, sWih, sWhh, s_b,
                                               wqih, wqhh, bq, wsih, wshh, bs);
    lstm_kernel<<<2304, 128, 0, stream>>>(sf, q_tok, emb_h, wsih, wshh, bs, wqih, wqhh, bq, hs, hq);
    gemm_g1234<<<512, 512, 0, stream>>>(hs, hq, g1wp, bias8, g2w, g2b, g3w, g3b, g4w, g4b, act2);
    f123s_kernel<<<256, 512, 0, stream>>>(act2, f1w, f1b, f2w, f2b, f3w, f3b, (float*)d_out);
}

// Round 10
// 319.135 us; speedup vs baseline: 1.2349x; 1.0010x over previous
//
#include <hip/hip_runtime.h>
#include <stdint.h>
#include <stddef.h>

typedef __fp16 f16;
typedef __attribute__((ext_vector_type(8))) __fp16 half8;
typedef __attribute__((ext_vector_type(4))) __fp16 half4;
typedef __attribute__((ext_vector_type(4))) float f32x4;
typedef unsigned int u32;

static __device__ __forceinline__ f32x4 mfma16(half8 a, half8 b, f32x4 c) {
    return __builtin_amdgcn_mfma_f32_16x16x32_f16(a, b, c, 0, 0, 0);
}
static __device__ __forceinline__ float fexp2(float x) { float r; asm("v_exp_f32 %0, %1" : "=v"(r) : "v"(x)); return r; }
static __device__ __forceinline__ float frcp(float x)  { float r; asm("v_rcp_f32 %0, %1" : "=v"(r) : "v"(x)); return r; }

static constexpr float L2E  = 1.4426950408889634f;
static constexpr float L2E2 = 2.8853900817779268f;

static constexpr int LDA = 264;    // LDS row stride (f16)
static constexpr int LDF2 = 520;

// ---------------- workspace layout (bytes) ----------------
static constexpr size_t OFF_EMB   = 0;
static constexpr size_t OFF_WQIH  = 3200000;
static constexpr size_t OFF_WQHH  = OFF_WQIH + 8192;
static constexpr size_t OFF_WSIH  = OFF_WQHH + 8192;
static constexpr size_t OFF_WSHH  = OFF_WSIH + 8192;
static constexpr size_t OFF_BQ    = OFF_WSHH + 8192;
static constexpr size_t OFF_BS    = OFF_BQ + 512;
static constexpr size_t OFF_G1WP  = OFF_BS + 512;
static constexpr size_t OFF_BIAS8 = OFF_G1WP + 32768;
static constexpr size_t OFF_G2W   = OFF_BIAS8 + 8192;
static constexpr size_t OFF_G3W   = OFF_G2W + 131072;
static constexpr size_t OFF_G4W   = OFF_G3W + 131072;
static constexpr size_t OFF_F1W   = OFF_G4W + 131072;
static constexpr size_t OFF_F2W   = OFF_F1W + 131072;
static constexpr size_t OFF_F3W   = OFF_F2W + 262144;
static constexpr size_t OFF_HS    = OFF_F3W + 1024000;
static constexpr size_t OFF_HQ    = OFF_HS + 2097152;
static constexpr size_t OFF_GO    = OFF_HQ + 262144;       // 4096*256*2 = 2MB
static constexpr size_t WS_NEED   = OFF_GO + 2097152;

// ---------------- fused fp32->fp16 conversion + small prep ----------------
struct CvtJobs { const float* src[7]; f16* dst[7]; int n[7]; };

__global__ __launch_bounds__(256) void cvt_prep(
    CvtJobs j,
    const float* __restrict__ g1W, const float* __restrict__ g1b,
    f16* __restrict__ wp, float* __restrict__ bias8,
    const float* __restrict__ qWih, const float* __restrict__ qWhh, const float* __restrict__ qb,
    const float* __restrict__ sWih, const float* __restrict__ sWhh, const float* __restrict__ sb,
    f16* __restrict__ wqih, f16* __restrict__ wqhh, float* __restrict__ bq,
    f16* __restrict__ wsih, f16* __restrict__ wshh, float* __restrict__ bs)
{
    int t = threadIdx.x;
    if (blockIdx.y < 7) {
        int jb = blockIdx.y;
        int i = (blockIdx.x * 256 + t) * 8;
        if (i >= j.n[jb]) return;
        const float* s = j.src[jb] + i;
        f32x4 a = *(const f32x4*)s;
        f32x4 b = *(const f32x4*)(s + 4);
        half8 o;
        o[0]=(f16)a[0]; o[1]=(f16)a[1]; o[2]=(f16)a[2]; o[3]=(f16)a[3];
        o[4]=(f16)b[0]; o[5]=(f16)b[1]; o[6]=(f16)b[2]; o[7]=(f16)b[3];
        *(half8*)(j.dst[jb] + i) = o;
        return;
    }
    if (blockIdx.x == 0) {
        int col = t;
        for (int k = 0; k < 64; k++) wp[col * 64 + k] = (f16)g1W[col * 65 + k];
        float wpos = g1W[col * 65 + 64];
        float b = g1b[col];
        for (int i = 0; i < 8; i++) bias8[i * 256 + col] = b + (float)i * wpos;
    } else if (blockIdx.x == 1) {
        for (int i = t; i < 4096; i += 256) {
            int row = i >> 5;
            float s = (row < 64 || row >= 96) ? -L2E : L2E2;
            wqih[i] = (f16)(qWih[i] * s);
            wqhh[i] = (f16)(qWhh[i] * s);
            wsih[i] = (f16)(sWih[i] * s);
            wshh[i] = (f16)(sWhh[i] * s);
        }
        if (t < 128) {
            float s = (t < 64 || t >= 96) ? -L2E : L2E2;
            bq[t] = qb[t] * s;
            bs[t] = sb[t] * s;
        }
    }
}

// ---------------- fused LSTM: 16 samples per 2-wave block (unchanged, control) ----------------
struct SfPtrs { const int* p[8]; };

__global__ __launch_bounds__(128) void lstm_kernel(
    SfPtrs sf, const int* __restrict__ qtok, const f16* __restrict__ emb_h,
    const f16* __restrict__ wih_sf, const f16* __restrict__ whh_sf, const float* __restrict__ b_sf,
    const f16* __restrict__ wih_q,  const f16* __restrict__ whh_q,  const float* __restrict__ b_q,
    f16* __restrict__ hs_out, f16* __restrict__ hq_out)
{
    __shared__ __align__(16) char hbuf[2][16 * 80];
    int tid = threadIdx.x;
    int w = tid >> 6, lane = tid & 63;
    int c15 = lane & 15, kq = lane >> 4;
    int sbase = blockIdx.x * 16;
    bool isq = sbase >= 32768;
    const f16* wih = isq ? wih_q : wih_sf;
    const f16* whh = isq ? whh_q : whh_sf;
    const float* bvec = isq ? b_q : b_sf;

    half8 wi[4], wh[4];
    f32x4 bc[4];
    #pragma unroll
    for (int jg = 0; jg < 4; jg++) {
        int row = (2 * jg + w) * 16 + c15;
        wi[jg] = *(const half8*)(wih + row * 32 + kq * 8);
        wh[jg] = *(const half8*)(whh + row * 32 + kq * 8);
        bc[jg] = *(const f32x4*)(bvec + (2 * jg + w) * 16 + kq * 4);
    }
    int sg = sbase + c15;
    const int* tp;
    if (isq) tp = qtok + (sg - 32768) * 64;
    else     tp = sf.p[sg >> 12] + (sg & 4095) * 64;

    for (int i = tid; i < 640; i += 128) ((u32*)hbuf[0])[i] = 0;
    __syncthreads();

    float cst[4] = {};
    int rb = 0;
    const int hoff_r = c15 * 80 + kq * 16;
    const int hoff_w = c15 * 80 + w * 32 + kq * 8;

    half8 xf = *(const half8*)(emb_h + (size_t)tp[0] * 32 + kq * 8);

    #pragma unroll 1
    for (int t = 0; t < 64; t++) {
        half8 hf = *(const half8*)(hbuf[rb] + hoff_r);
        f32x4 acc[4];
        #pragma unroll
        for (int jg = 0; jg < 4; jg++) acc[jg] = mfma16(wi[jg], xf, bc[jg]);
        #pragma unroll
        for (int jg = 0; jg < 4; jg++) acc[jg] = mfma16(wh[jg], hf, acc[jg]);
        if (t < 63) {
            int tk = tp[t + 1];
            xf = *(const half8*)(emb_h + (size_t)tk * 32 + kq * 8);
        }
        half4 hp;
        #pragma unroll
        for (int r = 0; r < 4; r++) {
            float ei = fexp2(acc[0][r]);
            float ef = fexp2(acc[1][r]);
            float eg = fexp2(acc[2][r]);
            float eo = fexp2(acc[3][r]);
            float t1 = 1.f + ei, t2 = 1.f + ef, t5 = 1.f + eo;
            float eg1 = eg + 1.f, egm = eg - 1.f;
            float t1e = t1 * eg1;
            float num = fmaf(egm, t2, cst[r] * t1e);
            float cn  = num * frcp(t1e * t2);
            cst[r] = cn;
            float ec  = fexp2(cn * L2E2);
            hp[r] = (f16)((ec - 1.f) * frcp((ec + 1.f) * t5));
        }
        *(half4*)(hbuf[rb ^ 1] + hoff_w) = hp;
        __syncthreads();
        rb ^= 1;
    }
    if (w == 0) {
        half8 hv = *(const half8*)(hbuf[rb] + hoff_r);
        if (isq) *(half8*)(hq_out + (size_t)(sg - 32768) * 32 + kq * 8) = hv;
        else     *(half8*)(hs_out + (size_t)sg * 32 + kq * 8) = hv;
    }
}

// ---------------- fused g1..g4 + relation-sum: relation-major 64-row strips ----------------
// Block b owns samples b*8..b*8+7 for ALL 8 relations: local row l = rel*8 + samp.
// After g4 (in LDS), reduce over rel in-block and write go[4096][256] directly.
template<bool TOGLOBAL>
static __device__ __forceinline__ void layer256(
    const f16 (* __restrict__ src)[LDA], f16 (* __restrict__ dst)[LDA],
    const f16* __restrict__ W, const float* __restrict__ bias,
    int wm, int wn, int c15, int kq)
{
    f32x4 acc[2][4];
    #pragma unroll
    for (int a = 0; a < 2; a++)
        #pragma unroll
        for (int b = 0; b < 4; b++) acc[a][b] = (f32x4){0.f, 0.f, 0.f, 0.f};
    #pragma unroll
    for (int k0 = 0; k0 < 8; k0++) {
        half8 av[2], bv[4];
        #pragma unroll
        for (int fm = 0; fm < 2; fm++) av[fm] = *(const half8*)(&src[wm * 32 + fm * 16 + c15][k0 * 32 + kq * 8]);
        #pragma unroll
        for (int fn = 0; fn < 4; fn++) bv[fn] = *(const half8*)(W + (size_t)(wn * 64 + fn * 16 + c15) * 256 + k0 * 32 + kq * 8);
        #pragma unroll
        for (int fm = 0; fm < 2; fm++)
            #pragma unroll
            for (int fn = 0; fn < 4; fn++) acc[fm][fn] = mfma16(av[fm], bv[fn], acc[fm][fn]);
    }
    #pragma unroll
    for (int fn = 0; fn < 4; fn++) {
        int col = wn * 64 + fn * 16 + c15;
        float bb = bias[col];
        #pragma unroll
        for (int fm = 0; fm < 2; fm++)
            #pragma unroll
            for (int r = 0; r < 4; r++) {
                float v = fmaxf(acc[fm][fn][r] + bb, 0.f);
                dst[wm * 32 + fm * 16 + kq * 4 + r][col] = (f16)v;
            }
    }
}

__global__ __launch_bounds__(512) void gemm_g1234(
    const f16* __restrict__ hs, const f16* __restrict__ hq,
    const f16* __restrict__ g1wp, const float* __restrict__ bias8,
    const f16* __restrict__ g2w, const float* __restrict__ g2b,
    const f16* __restrict__ g3w, const float* __restrict__ g3b,
    const f16* __restrict__ g4w, const float* __restrict__ g4b,
    f16* __restrict__ go)
{
    __shared__ __align__(16) f16 actA[64][LDA];
    __shared__ __align__(16) f16 actB[64][LDA];
    const int wv = threadIdx.x >> 6, lane = threadIdx.x & 63;
    const int c15 = lane & 15, kq = lane >> 4;
    const int wm = wv >> 2, wn = wv & 3;
    const int b8 = blockIdx.x * 8;   // first sample of this block

    { // g1: K=64 (hs || hq); local row l = wm*32+fm*16+c15 -> rel=l>>3, samp=b8+(l&7)
        f32x4 acc[2][4];
        #pragma unroll
        for (int a = 0; a < 2; a++)
            #pragma unroll
            for (int b = 0; b < 4; b++) acc[a][b] = (f32x4){0.f, 0.f, 0.f, 0.f};
        half8 av[2], bv[4];
        half8 avq = *(const half8*)(hq + (size_t)(b8 + (c15 & 7)) * 32 + kq * 8);  // same for both fm
        #pragma unroll
        for (int fm = 0; fm < 2; fm++) {
            int l = wm * 32 + fm * 16 + c15;
            int rowg = (l >> 3) * 4096 + b8 + (l & 7);
            av[fm] = *(const half8*)(hs + (size_t)rowg * 32 + kq * 8);
        }
        #pragma unroll
        for (int fn = 0; fn < 4; fn++) bv[fn] = *(const half8*)(g1wp + (size_t)(wn * 64 + fn * 16 + c15) * 64 + kq * 8);
        #pragma unroll
        for (int fm = 0; fm < 2; fm++)
            #pragma unroll
            for (int fn = 0; fn < 4; fn++) acc[fm][fn] = mfma16(av[fm], bv[fn], acc[fm][fn]);
        #pragma unroll
        for (int fn = 0; fn < 4; fn++) bv[fn] = *(const half8*)(g1wp + (size_t)(wn * 64 + fn * 16 + c15) * 64 + 32 + kq * 8);
        #pragma unroll
        for (int fm = 0; fm < 2; fm++)
            #pragma unroll
            for (int fn = 0; fn < 4; fn++) acc[fm][fn] = mfma16(avq, bv[fn], acc[fm][fn]);
        #pragma unroll
        for (int fn = 0; fn < 4; fn++) {
            int col = wn * 64 + fn * 16 + c15;
            #pragma unroll
            for (int fm = 0; fm < 2; fm++) {
                int rel = wm * 4 + fm * 2 + (kq >> 1);   // = (wm*32+fm*16+kq*4)>>3
                float bb = bias8[rel * 256 + col];
                #pragma unroll
                for (int r = 0; r < 4; r++)
                    actA[wm * 32 + fm * 16 + kq * 4 + r][col] = (f16)fmaxf(acc[fm][fn][r] + bb, 0.f);
            }
        }
    }
    __syncthreads();
    layer256<false>(actA, actB, g2w, g2b, wm, wn, c15, kq);
    __syncthreads();
    layer256<false>(actB, actA, g3w, g3b, wm, wn, c15, kq);
    __syncthreads();
    layer256<false>(actA, actB, g4w, g4b, wm, wn, c15, kq);
    __syncthreads();
    // relation-sum: wave wv handles sample slot wv (8 waves = 8 samples);
    // lane covers cols lane*4..+3; rows rel*8+wv, rel=0..7
    {
        float s0 = 0.f, s1 = 0.f, s2 = 0.f, s3 = 0.f;
        #pragma unroll
        for (int rel = 0; rel < 8; rel++) {
            half4 v = *(const half4*)(&actB[rel * 8 + wv][lane * 4]);
            s0 += (float)v[0]; s1 += (float)v[1]; s2 += (float)v[2]; s3 += (float)v[3];
        }
        half4 o; o[0] = (f16)s0; o[1] = (f16)s1; o[2] = (f16)s2; o[3] = (f16)s3;
        *(half4*)(go + (size_t)(b8 + wv) * 256 + lane * 4) = o;
    }
}

// ---------------- fused f1 + f2 + f3: 16-row strips, 16 waves ----------------
__global__ __launch_bounds__(1024) void f123s_kernel(
    const f16* __restrict__ go,
    const f16* __restrict__ f1w, const float* __restrict__ f1b,
    const f16* __restrict__ f2w, const float* __restrict__ f2b,
    const f16* __restrict__ f3w, const float* __restrict__ f3b,
    float* __restrict__ out)
{
    __shared__ __align__(16) f16 smbuf[16][LDA];
    __shared__ __align__(16) f16 f1buf[16][LDA];
    __shared__ __align__(16) f16 f2buf[16][LDF2];
    const int b0 = blockIdx.x * 16;

    { // stage go rows b0..b0+15 into LDS (512 of 1024 threads)
        int t = threadIdx.x;
        if (t < 512) {
            int r = t >> 5, cb = (t & 31) * 8;
            *(half8*)(&smbuf[r][cb]) = *(const half8*)(go + (size_t)(b0 + r) * 256 + cb);
        }
    }
    __syncthreads();
    const int wv = threadIdx.x >> 6, lane = threadIdx.x & 63;
    const int c15 = lane & 15, kq = lane >> 4;

    { // f1: wave wv -> cols wv*16 + c15
        f32x4 acc = (f32x4){0.f, 0.f, 0.f, 0.f};
        #pragma unroll
        for (int k0 = 0; k0 < 8; k0++) {
            half8 a = *(const half8*)(&smbuf[c15][k0 * 32 + kq * 8]);
            half8 bv = *(const half8*)(f1w + (size_t)(wv * 16 + c15) * 256 + k0 * 32 + kq * 8);
            acc = mfma16(a, bv, acc);
        }
        int col = wv * 16 + c15;
        float bb = f1b[col];
        #pragma unroll
        for (int r = 0; r < 4; r++)
            f1buf[kq * 4 + r][col] = (f16)fmaxf(acc[r] + bb, 0.f);
    }
    __syncthreads();
    { // f2: cols wv*32 + fn*16, fn<2
        f32x4 acc[2];
        acc[0] = (f32x4){0.f, 0.f, 0.f, 0.f}; acc[1] = acc[0];
        #pragma unroll
        for (int k0 = 0; k0 < 8; k0++) {
            half8 a = *(const half8*)(&f1buf[c15][k0 * 32 + kq * 8]);
            #pragma unroll
            for (int fn = 0; fn < 2; fn++) {
                half8 bv = *(const half8*)(f2w + (size_t)(wv * 32 + fn * 16 + c15) * 256 + k0 * 32 + kq * 8);
                acc[fn] = mfma16(a, bv, acc[fn]);
            }
        }
        #pragma unroll
        for (int fn = 0; fn < 2; fn++) {
            int col = wv * 32 + fn * 16 + c15;
            float bb = f2b[col];
            #pragma unroll
            for (int r = 0; r < 4; r++)
                f2buf[kq * 4 + r][col] = (f16)fmaxf(acc[fn][r] + bb, 0.f);
        }
    }
    __syncthreads();
    { // f3: cols wv*64 + fn*16, fn<4; N=1000 tail clamped/masked
        f32x4 acc[4];
        #pragma unroll
        for (int b = 0; b < 4; b++) acc[b] = (f32x4){0.f, 0.f, 0.f, 0.f};
        #pragma unroll
        for (int k0 = 0; k0 < 16; k0++) {
            half8 a = *(const half8*)(&f2buf[c15][k0 * 32 + kq * 8]);
            #pragma unroll
            for (int fn = 0; fn < 4; fn++) {
                int col = wv * 64 + fn * 16 + c15;
                int cl = col < 1000 ? col : 999;
                half8 bv = *(const half8*)(f3w + (size_t)cl * 512 + k0 * 32 + kq * 8);
                acc[fn] = mfma16(a, bv, acc[fn]);
            }
        }
        #pragma unroll
        for (int fn = 0; fn < 4; fn++) {
            int col = wv * 64 + fn * 16 + c15;
            if (col < 1000) {
                float bb = f3b[col];
                #pragma unroll
                for (int r = 0; r < 4; r++)
                    out[(size_t)(b0 + kq * 4 + r) * 1000 + col] = acc[fn][r] + bb;
            }
        }
    }
}

// ---------------- launcher ----------------
extern "C" void kernel_launch(void* const* d_in, const int* in_sizes, int n_in,
                              void* d_out, int out_size, void* d_ws, size_t ws_size,
                              hipStream_t stream)
{
    if (ws_size < WS_NEED) return;
    const int* q_tok = (const int*)d_in[0];
    SfPtrs sf;
    for (int i = 0; i < 8; i++) sf.p[i] = (const int*)d_in[1 + i];
    const float* emb_f = (const float*)d_in[9];
    const float* qWih = (const float*)d_in[10];
    const float* qWhh = (const float*)d_in[11];
    const float* q_b  = (const float*)d_in[12];
    const float* sWih = (const float*)d_in[13];
    const float* sWhh = (const float*)d_in[14];
    const float* s_b  = (const float*)d_in[15];
    const float* g1W  = (const float*)d_in[16];
    const float* g1b  = (const float*)d_in[17];
    const float* g2W  = (const float*)d_in[18];
    const float* g2b  = (const float*)d_in[19];
    const float* g3W  = (const float*)d_in[20];
    const float* g3b  = (const float*)d_in[21];
    const float* g4W  = (const float*)d_in[22];
    const float* g4b  = (const float*)d_in[23];
    const float* f1W  = (const float*)d_in[24];
    const float* f1b  = (const float*)d_in[25];
    const float* f2W  = (const float*)d_in[26];
    const float* f2b  = (const float*)d_in[27];
    const float* f3W  = (const float*)d_in[28];
    const float* f3b  = (const float*)d_in[29];

    char* ws = (char*)d_ws;
    f16* emb_h = (f16*)(ws + OFF_EMB);
    f16* wqih  = (f16*)(ws + OFF_WQIH);
    f16* wqhh  = (f16*)(ws + OFF_WQHH);
    f16* wsih  = (f16*)(ws + OFF_WSIH);
    f16* wshh  = (f16*)(ws + OFF_WSHH);
    float* bq  = (float*)(ws + OFF_BQ);
    float* bs  = (float*)(ws + OFF_BS);
    f16* g1wp  = (f16*)(ws + OFF_G1WP);
    float* bias8 = (float*)(ws + OFF_BIAS8);
    f16* g2w = (f16*)(ws + OFF_G2W);
    f16* g3w = (f16*)(ws + OFF_G3W);
    f16* g4w = (f16*)(ws + OFF_G4W);
    f16* f1w = (f16*)(ws + OFF_F1W);
    f16* f2w = (f16*)(ws + OFF_F2W);
    f16* f3w = (f16*)(ws + OFF_F3W);
    f16* hs  = (f16*)(ws + OFF_HS);
    f16* hq  = (f16*)(ws + OFF_HQ);
    f16* go  = (f16*)(ws + OFF_GO);

    CvtJobs cj;
    const float* srcs[7] = {emb_f, g2W, g3W, g4W, f1W, f2W, f3W};
    f16* dsts[7]         = {emb_h, g2w, g3w, g4w, f1w, f2w, f3w};
    int ns[7] = {1600000, 65536, 65536, 65536, 65536, 131072, 512000};
    for (int i = 0; i < 7; i++) { cj.src[i] = srcs[i]; cj.dst[i] = dsts[i]; cj.n[i] = ns[i]; }

    cvt_prep<<<dim3(782, 8), 256, 0, stream>>>(cj, g1W, g1b, g1wp, bias8,
                                               qWih, qWhh, q_b, sWih, sWhh, s_b,
                                               wqih, wqhh, bq, wsih, wshh, bs);
    lstm_kernel<<<2304, 128, 0, stream>>>(sf, q_tok, emb_h, wsih, wshh, bs, wqih, wqhh, bq, hs, hq);
    gemm_g1234<<<512, 512, 0, stream>>>(hs, hq, g1wp, bias8, g2w, g2b, g3w, g3b, g4w, g4b, go);
    f123s_kernel<<<256, 1024, 0, stream>>>(go, f1w, f1b, f2w, f2b, f3w, f3b, (float*)d_out);
}